// Round 30
// baseline (982.709 us; speedup 1.0000x reference)
//
#include <hip/hip_runtime.h>
#include <math.h>

// ---------------------------------------------------------------------------
// ParallelTransformerAEP forward.
// R29: mfma_dual_silu_k switched to mfma_f32_32x32x16_bf16 (2x FLOP per
//      instruction): halves MFMA instruction count per K-tile (32->16) at
//      identical FLOPs/reads/regs -- targets the 80% combined issue pressure
//      (MfmaUtil 34 + VALUBusy 46). C/D layout per guide (m74/m101):
//      col=lane&31, row=(reg&3)+8*(reg>>2)+4*(lane>>5). Rest = R28 (950 us).
// ---------------------------------------------------------------------------

namespace {
constexpr int SEQ    = 512;
constexpr int NBATCH = 32;
constexpr int DIMM   = 512;
constexpr int NHEAD  = 8;
constexpr int FFIN   = 2048;
constexpr int NFUSED = 4736;
constexpr int NROWS  = NBATCH * SEQ;   // 16384
constexpr int QKVC   = 640;            // 512 q + 64 k + 64 v
}

typedef __bf16 bf16x8 __attribute__((ext_vector_type(8)));
typedef float f32x4 __attribute__((ext_vector_type(4)));
typedef float f32x16 __attribute__((ext_vector_type(16)));
typedef unsigned short ushort8 __attribute__((ext_vector_type(8)));

static __device__ __forceinline__ unsigned short bfhi(float v, float* hf) {
    __bf16 h = (__bf16)v;
    *hf = (float)h;
    return __builtin_bit_cast(unsigned short, h);
}
static __device__ __forceinline__ unsigned short bflo(float v, float hf) {
    __bf16 l = (__bf16)(v - hf);
    return __builtin_bit_cast(unsigned short, l);
}

// 16-byte global->LDS DMA; LDS dest = wave-uniform base + lane*16.
static __device__ __forceinline__ void gload16(const unsigned short* g,
                                               unsigned short* l) {
    __builtin_amdgcn_global_load_lds(
        (const __attribute__((address_space(1))) void*)g,
        (__attribute__((address_space(3))) void*)l,
        16, 0, 0);
}

// ------------------------- build x = page * item ---------------------------
__global__ __launch_bounds__(512) void build_x_k(
    const int* __restrict__ page_in, const int* __restrict__ item_in,
    const int* __restrict__ item_meta_in, const int* __restrict__ page_meta_in,
    const float* __restrict__ pwide, const float* __restrict__ iwide,
    const float* __restrict__ page_emb, const float* __restrict__ page_meta_emb,
    const float* __restrict__ item_emb, const float* __restrict__ item_meta_emb,
    const float* __restrict__ item_pre_emb,
    const float* __restrict__ pW, const float* __restrict__ pb,
    const float* __restrict__ pg, const float* __restrict__ pbeta,
    const float* __restrict__ iW, const float* __restrict__ ib,
    const float* __restrict__ ig, const float* __restrict__ ibeta,
    float* __restrict__ x)
{
    const int row = blockIdx.x;
    const int b = row >> 9;
    const int s = row & 511;
    const int d = threadIdx.x;
    const float BNS = 0.9999950000374997f;   // 1/sqrt(1+1e-5)

    float pv, iv;
    if (d < 384) {
        pv = page_emb[(size_t)page_in[row] * 384 + d];
    } else if (d < 448) {
        pv = page_meta_emb[(size_t)page_meta_in[row] * 64 + (d - 384)];
    } else {
        const int dd = d - 448;
        float acc = pb[dd];
        #pragma unroll
        for (int c = 0; c < 8; ++c) {
            float w  = pwide[((size_t)b * 8 + c) * SEQ + s];
            float wn = w * BNS * pg[c] + pbeta[c];
            acc += wn * pW[c * 64 + dd];
        }
        pv = acc > 0.f ? acc : 0.2f * acc;
    }
    if (d < 320) {
        iv = item_emb[(size_t)item_in[row] * 320 + d];
    } else if (d < 384) {
        iv = item_meta_emb[(size_t)item_meta_in[row] * 64 + (d - 320)];
    } else if (d < 448) {
        iv = item_pre_emb[(size_t)item_in[row] * 64 + (d - 384)];
    } else {
        const int dd = d - 448;
        float acc = ib[dd];
        #pragma unroll
        for (int c = 0; c < 8; ++c) {
            float w  = iwide[((size_t)b * 8 + c) * SEQ + s];
            float wn = w * BNS * ig[c] + ibeta[c];
            acc += wn * iW[c * 64 + dd];
        }
        iv = acc > 0.f ? acc : 0.2f * acc;
    }
    x[(size_t)row * DIMM + d] = pv * iv;
}

// ------------------------------ trig table ---------------------------------
__global__ __launch_bounds__(256) void trig_k(float* __restrict__ cost,
                                              float* __restrict__ sint)
{
    const int idx = blockIdx.x * 256 + threadIdx.x;   // 16384 = 512 x 32
    const int s = idx >> 5, j = idx & 31;
    float invf = powf(10000.0f, -(float)j * (1.0f / 32.0f));
    float ang = (float)s * invf;
    float sn, cs;
    sincosf(ang, &sn, &cs);
    cost[idx] = cs;
    sint[idx] = sn;
}

// ------------------------------ LayerNorm -> bf16 (hi only) ----------------
__global__ __launch_bounds__(256) void ln_k(const float* __restrict__ x,
                                            unsigned short* __restrict__ xnh,
                                            const float* __restrict__ g)
{
    const int row = blockIdx.x;
    const int t = threadIdx.x;
    const float* xr = x + (size_t)row * DIMM;
    __shared__ float red[4];

    float v0 = xr[t], v1 = xr[t + 256];
    float s = v0 + v1;
    #pragma unroll
    for (int o = 32; o; o >>= 1) s += __shfl_xor(s, o);
    if ((t & 63) == 0) red[t >> 6] = s;
    __syncthreads();
    float mu = (red[0] + red[1] + red[2] + red[3]) * (1.0f / 512.0f);
    __syncthreads();

    float d0 = v0 - mu, d1 = v1 - mu;
    float vs = d0 * d0 + d1 * d1;
    #pragma unroll
    for (int o = 32; o; o >>= 1) vs += __shfl_xor(vs, o);
    if ((t & 63) == 0) red[t >> 6] = vs;
    __syncthreads();
    float var = (red[0] + red[1] + red[2] + red[3]) * (1.0f / 512.0f);
    float r = 1.0f / sqrtf(var + 1e-5f);

    const size_t base = (size_t)row * DIMM;
    float o0 = d0 * r * g[t];
    float o1 = d1 * r * g[t + 256];
    float hf;
    xnh[base + t]       = bfhi(o0, &hf);
    xnh[base + t + 256] = bfhi(o1, &hf);
}

// ------- fused weight transpose+split for all four regions of one layer ----
__global__ __launch_bounds__(256) void wconv_all_k(
    const float* __restrict__ Wf, const float* __restrict__ Wa,
    const float* __restrict__ Wff,
    unsigned short* __restrict__ WqTh, unsigned short* __restrict__ WqTl,
    unsigned short* __restrict__ WdTh, unsigned short* __restrict__ WaTh,
    unsigned short* __restrict__ WfTh)
{
    __shared__ float tile[64][65];
    const int bid = blockIdx.x;
    const int t   = threadIdx.x;

    const float* W;
    unsigned short* Th;
    unsigned short* Tl = nullptr;
    int ldw, col0, ldt, nt, kt;
    bool split = false;

    if (bid < 80) {                 // Wq
        W = Wf; ldw = NFUSED; col0 = 0; Th = WqTh; Tl = WqTl; ldt = DIMM;
        split = true;
        nt = bid % 10; kt = bid / 10;
    } else if (bid < 592) {         // Wd
        int b = bid - 80;
        W = Wf; ldw = NFUSED; col0 = 640; Th = WdTh; ldt = DIMM;
        nt = b & 63; kt = b >> 6;
    } else if (bid < 656) {         // Wa
        int b = bid - 592;
        W = Wa; ldw = DIMM; col0 = 0; Th = WaTh; ldt = DIMM;
        nt = b & 7; kt = b >> 3;
    } else {                        // Wff
        int b = bid - 656;
        W = Wff; ldw = DIMM; col0 = 0; Th = WfTh; ldt = FFIN;
        nt = b & 7; kt = b >> 3;
    }
    nt <<= 6; kt <<= 6;

    #pragma unroll
    for (int i = 0; i < 16; ++i) {
        int flat = i * 256 + t;
        int r = flat >> 6, c = flat & 63;
        tile[r][c] = W[(size_t)(kt + r) * ldw + col0 + nt + c];
    }
    __syncthreads();
    #pragma unroll
    for (int i = 0; i < 2; ++i) {
        int flat = i * 256 + t;
        int n = flat >> 3, ck = (flat & 7) << 3;
        ushort8 hv, lv;
        #pragma unroll
        for (int j = 0; j < 8; ++j) {
            float v = tile[ck + j][n];
            float hf;
            hv[j] = bfhi(v, &hf);
            if (split) lv[j] = bflo(v, hf);
        }
        size_t o = (size_t)(nt + n) * ldt + kt + ck;
        *(ushort8*)&Th[o] = hv;
        if (split) *(ushort8*)&Tl[o] = lv;
    }
}

// ---- MFMA qkv GEMM + fused RoPE epilogue ----------------------------------
__global__ __launch_bounds__(256, 4) void mfma_qkv_rope_k(
    const unsigned short* __restrict__ Ah,
    const unsigned short* __restrict__ BTh, const unsigned short* __restrict__ BTl,
    const float* __restrict__ cost, const float* __restrict__ sint,
    unsigned short* __restrict__ qh,
    unsigned short* __restrict__ kh, unsigned short* __restrict__ kl,
    unsigned short* __restrict__ vT)
{
    __shared__ unsigned short smem[128 * 64 + 64 * 64 + 64 * 64];  // 32 KB
    unsigned short* sA  = smem;
    unsigned short* sBh = smem + 128 * 64;
    unsigned short* sBl = smem + 128 * 64 + 64 * 64;
    float* tileF = (float*)smem;   // 8192 fp32 = full 32 KB, reused post-loop

    const int n0 = blockIdx.x << 6;
    const int m0 = blockIdx.y << 7;
    const int t  = threadIdx.x;
    const int l  = t & 63;
    const int w  = t >> 6;
    const int wm = w >> 1, wn = w & 1;
    const int lr = l & 15, lg = l >> 4;
    const int lm = l >> 3;      // row within 8-row DMA segment
    const int lc = l & 7;       // 16B chunk within row

    f32x4 acc[4][2];
    #pragma unroll
    for (int fm = 0; fm < 4; ++fm)
        #pragma unroll
        for (int fn = 0; fn < 2; ++fn) acc[fm][fn] = (f32x4)0.f;

    for (int k0 = 0; k0 < DIMM; k0 += 64) {
        __syncthreads();
        // A: 16 segments of 8 rows; wave w handles segments w*4..w*4+3
        #pragma unroll
        for (int j = 0; j < 4; ++j) {
            int seg = w * 4 + j;
            int m = seg * 8 + lm;
            gload16(&Ah[(size_t)(m0 + m) * DIMM + k0 + ((lc ^ (m & 7)) << 3)],
                    &sA[seg * 512]);
        }
        // Bh/Bl: 8 segments each; wave w handles segments w*2..w*2+1
        #pragma unroll
        for (int j = 0; j < 2; ++j) {
            int seg = w * 2 + j;
            int n = seg * 8 + lm;
            int soff = (lc ^ (n & 7)) << 3;
            gload16(&BTh[(size_t)(n0 + n) * DIMM + k0 + soff], &sBh[seg * 512]);
            gload16(&BTl[(size_t)(n0 + n) * DIMM + k0 + soff], &sBl[seg * 512]);
        }
        __syncthreads();

        #pragma unroll
        for (int kk = 0; kk < 2; ++kk) {
            const int c = kk * 4 + lg;
            bf16x8 af[4];
            #pragma unroll
            for (int fm = 0; fm < 4; ++fm) {
                int m = wm * 64 + fm * 16 + lr;
                int lidx = m * 64 + ((c ^ (m & 7)) << 3);
                af[fm] = *(bf16x8*)&sA[lidx];
            }
            bf16x8 bh[2], bl[2];
            #pragma unroll
            for (int fn = 0; fn < 2; ++fn) {
                int n = wn * 32 + fn * 16 + lr;
                int lidx = n * 64 + ((c ^ (n & 7)) << 3);
                bh[fn] = *(bf16x8*)&sBh[lidx];
                bl[fn] = *(bf16x8*)&sBl[lidx];
            }
            #pragma unroll
            for (int fm = 0; fm < 4; ++fm)
                #pragma unroll
                for (int fn = 0; fn < 2; ++fn) {
                    acc[fm][fn] = __builtin_amdgcn_mfma_f32_16x16x32_bf16(af[fm], bh[fn], acc[fm][fn], 0, 0, 0);
                    acc[fm][fn] = __builtin_amdgcn_mfma_f32_16x16x32_bf16(af[fm], bl[fn], acc[fm][fn], 0, 0, 0);
                }
        }
    }

    // ---- epilogue: acc -> fp32 LDS tile, rotation swizzle col=(d+s)&63 ----
    __syncthreads();
    #pragma unroll
    for (int fm = 0; fm < 4; ++fm)
        #pragma unroll
        for (int fn = 0; fn < 2; ++fn) {
            const int nl = wn * 32 + fn * 16 + lr;
            #pragma unroll
            for (int r = 0; r < 4; ++r) {
                const int ml = wm * 64 + fm * 16 + lg * 4 + r;
                tileF[ml * 64 + ((nl + ml) & 63)] = acc[fm][fn][r];
            }
        }
    __syncthreads();

    const int tid = n0 >> 6;        // 0..7 q heads, 8 = k, 9 = v
    const int gb  = m0 >> 9;        // batch (128-row tile stays in one batch)
    const int sb  = m0 & 511;       // s base within batch

    if (tid < 8) {
        // q: rope + 1/8 scale -> qh[((gb*8+tid)*512+s)*64+d]
        #pragma unroll 4
        for (int i = 0; i < 32; ++i) {
            int flat = i * 256 + t;
            int d = flat & 63, sl = flat >> 6;
            int s = sb + sl;
            float v  = tileF[sl * 64 + ((d + sl) & 63)];
            float vp = tileF[sl * 64 + (((d ^ 32) + sl) & 63)];
            float cs = cost[s * 32 + (d & 31)];
            float sn = sint[s * 32 + (d & 31)];
            float sgn = (d < 32) ? -1.f : 1.f;
            float o = (v * cs + sgn * vp * sn) * 0.125f;
            float hf;
            qh[(((size_t)gb * 8 + tid) * 512 + s) * 64 + d] = bfhi(o, &hf);
        }
    } else if (tid == 8) {
        // k: rope (no scale) -> kh/kl split
        #pragma unroll 4
        for (int i = 0; i < 32; ++i) {
            int flat = i * 256 + t;
            int d = flat & 63, sl = flat >> 6;
            int s = sb + sl;
            float v  = tileF[sl * 64 + ((d + sl) & 63)];
            float vp = tileF[sl * 64 + (((d ^ 32) + sl) & 63)];
            float cs = cost[s * 32 + (d & 31)];
            float sn = sint[s * 32 + (d & 31)];
            float sgn = (d < 32) ? -1.f : 1.f;
            float o = v * cs + sgn * vp * sn;
            float hf;
            size_t idx = ((size_t)gb * 512 + s) * 64 + d;
            kh[idx] = bfhi(o, &hf);
            kl[idx] = bflo(o, hf);
        }
    } else {
        // v: transposed store vT[(gb*64+d)*512 + s] (lanes sweep s: coalesced)
        #pragma unroll 4
        for (int i = 0; i < 32; ++i) {
            int flat = i * 256 + t;
            int sl = flat & 127, d = flat >> 7;
            float v = tileF[sl * 64 + ((d + sl) & 63)];
            float hf;
            vT[((size_t)gb * 64 + d) * 512 + sb + sl] = bfhi(v, &hf);
        }
    }
}

// ----- MFMA out GEMM: x += ctx@Wa + h@Wff (single bf16, 2-pass K) ----------
// BM=64 x BN=256; 1D grid 512 with XCD-chunked swizzle.
// Counted-vmcnt double buffer (R28). LDS 80KB, lb(256,2).
__global__ __launch_bounds__(256, 2) void mfma_out_k(
    const unsigned short* __restrict__ A1,
    const unsigned short* __restrict__ B1,
    const unsigned short* __restrict__ A2,
    const unsigned short* __restrict__ B2,
    float* __restrict__ X)
{
    __shared__ unsigned short sA[2][64 * 64];
    __shared__ unsigned short sB[2][256 * 64];

    const int bid = blockIdx.x;
    const int swz = (bid & 7) * 64 + (bid >> 3);
    const int n0 = (swz & 1) << 8;
    const int m0 = (swz >> 1) << 6;

    const int t  = threadIdx.x;
    const int l  = t & 63;
    const int w  = t >> 6;
    const int lr = l & 15, lg = l >> 4;
    const int lm = l >> 3;      // row within 8-row DMA segment
    const int lc = l & 7;       // 16B chunk within row

    f32x4 acc[4][4];
    #pragma unroll
    for (int fm = 0; fm < 4; ++fm)
        #pragma unroll
        for (int fn = 0; fn < 4; ++fn) acc[fm][fn] = (f32x4)0.f;

    // flattened K-tiles: 0..7 = pass0 (ctx@Wa, K=512), 8..39 = pass1 (h@Wff)
    auto stage = [&](int buf, int tt) {
        const unsigned short* pA = (tt < 8) ? A1 : A2;
        const unsigned short* pB = (tt < 8) ? B1 : B2;
        const int lda = (tt < 8) ? DIMM : FFIN;
        const int KK  = (tt < 8) ? DIMM : FFIN;
        const int k0  = ((tt < 8) ? tt : tt - 8) << 6;
        #pragma unroll
        for (int j = 0; j < 2; ++j) {
            int seg = w * 2 + j;
            int m = seg * 8 + lm;
            gload16(&pA[(size_t)(m0 + m) * lda + k0 + ((lc ^ (m & 7)) << 3)],
                    &sA[buf][seg * 512]);
        }
        #pragma unroll
        for (int j = 0; j < 8; ++j) {
            int seg = w * 8 + j;
            int n = seg * 8 + lm;
            gload16(&pB[(size_t)(n0 + n) * KK + k0 + ((lc ^ (n & 7)) << 3)],
                    &sB[buf][seg * 512]);
        }
    };

    auto compute = [&](int buf) {
        #pragma unroll
        for (int kk = 0; kk < 2; ++kk) {
            const int c = kk * 4 + lg;
            bf16x8 af[4];
            #pragma unroll
            for (int fm = 0; fm < 4; ++fm) {
                int m = fm * 16 + lr;
                int lidx = m * 64 + ((c ^ (m & 7)) << 3);
                af[fm] = *(bf16x8*)&sA[buf][lidx];
            }
            bf16x8 bfr[4];
            #pragma unroll
            for (int fn = 0; fn < 4; ++fn) {
                int n = w * 64 + fn * 16 + lr;
                int lidx = n * 64 + ((c ^ (n & 7)) << 3);
                bfr[fn] = *(bf16x8*)&sB[buf][lidx];
            }
            #pragma unroll
            for (int fm = 0; fm < 4; ++fm)
                #pragma unroll
                for (int fn = 0; fn < 4; ++fn)
                    acc[fm][fn] = __builtin_amdgcn_mfma_f32_16x16x32_bf16(af[fm], bfr[fn], acc[fm][fn], 0, 0, 0);
        }
    };

    stage(0, 0);
    asm volatile("s_waitcnt vmcnt(0)" ::: "memory");
    __builtin_amdgcn_sched_barrier(0);
    __builtin_amdgcn_s_barrier();
    int cur = 0;
    for (int tt = 0; tt < 39; ++tt) {
        stage(cur ^ 1, tt + 1);    // 10 DMAs issued, left in flight
        asm volatile("s_waitcnt vmcnt(10)" ::: "memory");  // tile tt landed
        __builtin_amdgcn_sched_barrier(0);
        __builtin_amdgcn_s_barrier();
        compute(cur);
        __builtin_amdgcn_s_barrier();   // all reads of buf done before overwrite
        cur ^= 1;
    }
    asm volatile("s_waitcnt vmcnt(0)" ::: "memory");
    __builtin_amdgcn_sched_barrier(0);
    __builtin_amdgcn_s_barrier();
    compute(cur);                  // last tile

    #pragma unroll
    for (int fm = 0; fm < 4; ++fm)
        #pragma unroll
        for (int fn = 0; fn < 4; ++fn) {
            const int n = n0 + w * 64 + fn * 16 + lr;
            #pragma unroll
            for (int r = 0; r < 4; ++r) {
                const int m = m0 + fm * 16 + lg * 4 + r;
                X[(size_t)m * DIMM + n] += acc[fm][fn][r];
            }
        }
}

// --- MFMA dual GEMM: h = silu(A@Wg)*(A@Wx), single bf16 -> bf16 ------------
// R29: 32x32x16 MFMA. Wave tile 64x32 = 2 MFMAs of 32x32 per GEMM.
// A/B frag: row/col = l&31, k-chunk = kk*2+(l>>5). C/D: col=lane&31,
// row=(reg&3)+8*(reg>>2)+4*(lane>>5). Staging/epilogue-store unchanged.
__global__ __launch_bounds__(256, 4) void mfma_dual_silu_k(
    const unsigned short* __restrict__ Ah,
    const unsigned short* __restrict__ WTh,
    unsigned short* __restrict__ Hh)
{
    __shared__ unsigned short sA[128 * 64];
    __shared__ unsigned short sBx[64 * 64];
    __shared__ unsigned short sBg[64 * 64];

    const int n0 = blockIdx.x << 6;
    const int m0 = blockIdx.y << 7;
    const int t  = threadIdx.x;
    const int l  = t & 63;
    const int w  = t >> 6;
    const int wm = w >> 1, wn = w & 1;
    const int l31 = l & 31;     // row/col within 32-tile
    const int lk  = l >> 5;     // k-half (0/1)
    const int lm = l >> 3;      // row within 8-row DMA segment
    const int lc = l & 7;       // 16B chunk within row

    f32x16 accX[2], accG[2];
    #pragma unroll
    for (int fm = 0; fm < 2; ++fm) {
        accX[fm] = (f32x16)0.f;
        accG[fm] = (f32x16)0.f;
    }

    for (int k0 = 0; k0 < DIMM; k0 += 64) {
        __syncthreads();
        // A: 16 segments of 8 rows; wave w handles segments w*4..w*4+3
        #pragma unroll
        for (int j = 0; j < 4; ++j) {
            int seg = w * 4 + j;
            int m = seg * 8 + lm;
            gload16(&Ah[(size_t)(m0 + m) * DIMM + k0 + ((lc ^ (m & 7)) << 3)],
                    &sA[seg * 512]);
        }
        // Bx/Bg: 8 segments each; wave w handles segments w*2..w*2+1
        #pragma unroll
        for (int j = 0; j < 2; ++j) {
            int seg = w * 2 + j;
            int n = seg * 8 + lm;
            int soff = (lc ^ (n & 7)) << 3;
            gload16(&WTh[(size_t)(n0 + n) * DIMM + k0 + soff], &sBx[seg * 512]);
            gload16(&WTh[(size_t)(2048 + n0 + n) * DIMM + k0 + soff], &sBg[seg * 512]);
        }
        __syncthreads();

        #pragma unroll
        for (int kk = 0; kk < 4; ++kk) {
            const int c = kk * 2 + lk;     // K=16 per MFMA: 2 chunks of 8
            bf16x8 af[2];
            #pragma unroll
            for (int fm = 0; fm < 2; ++fm) {
                int m = wm * 64 + fm * 32 + l31;
                int lidx = m * 64 + ((c ^ (m & 7)) << 3);
                af[fm] = *(bf16x8*)&sA[lidx];
            }
            int n = wn * 32 + l31;
            int bidx = n * 64 + ((c ^ (n & 7)) << 3);
            bf16x8 bx = *(bf16x8*)&sBx[bidx];
            bf16x8 bg = *(bf16x8*)&sBg[bidx];
            #pragma unroll
            for (int fm = 0; fm < 2; ++fm) {
                accX[fm] = __builtin_amdgcn_mfma_f32_32x32x16_bf16(af[fm], bx, accX[fm], 0, 0, 0);
                accG[fm] = __builtin_amdgcn_mfma_f32_32x32x16_bf16(af[fm], bg, accG[fm], 0, 0, 0);
            }
        }
    }

    // epilogue: silu into LDS tile with staging-style swizzle (32x32 C/D map)
    __syncthreads();
    #pragma unroll
    for (int fm = 0; fm < 2; ++fm) {
        const int nl = wn * 32 + l31;
        const int cc = nl >> 3;
        #pragma unroll
        for (int reg = 0; reg < 16; ++reg) {
            const int ml = wm * 64 + fm * 32 + (reg & 3) + 8 * (reg >> 2) + 4 * lk;
            float gv = accG[fm][reg];
            float xv = accX[fm][reg];
            float sig = 1.0f / (1.0f + __expf(-gv));
            float hv = gv * sig * xv;
            float hf;
            sA[ml * 64 + ((cc ^ (ml & 7)) << 3) + (nl & 7)] = bfhi(hv, &hf);
        }
    }
    __syncthreads();
    // coalesced 16B nontemporal stores: 128 rows x 8 chunks = 1024 x ushort8
    #pragma unroll
    for (int i = 0; i < 4; ++i) {
        int flat = i * 256 + t;
        int m = flat >> 3, c = flat & 7;
        ushort8 v = *(ushort8*)&sA[m * 64 + ((c ^ (m & 7)) << 3)];
        __builtin_nontemporal_store(v, (ushort8*)&Hh[(size_t)(m0 + m) * FFIN + n0 + c * 8]);
    }
}

// ------------------- attention: MFMA flash (per b,h,64 q-rows) -------------
// Masked-tile skip; QK = qh*(kh+kl) 2-product.
__global__ __launch_bounds__(256) void attn_mfma_k(
    const unsigned short* __restrict__ qh,
    const unsigned short* __restrict__ kh, const unsigned short* __restrict__ kl,
    const unsigned short* __restrict__ vT,
    unsigned short* __restrict__ ctxh,
    const int* __restrict__ vl)
{
    __shared__ unsigned short sKh[64 * 64];
    __shared__ unsigned short sKl[64 * 64];
    __shared__ unsigned short sVT[64 * 64];
    __shared__ unsigned short sP[64 * 64];

    const int i0 = blockIdx.x << 6;
    const int h  = blockIdx.y;
    const int b  = blockIdx.z;
    const int t  = threadIdx.x;
    const int l  = t & 63;
    const int w  = t >> 6;
    const int lr = l & 15, lg = l >> 4;
    const int VL = vl[b];
    const int ntiles = (VL + 63) >> 6;   // fully-masked tiles contribute 0

    bf16x8 qfh[2];
    {
        size_t base = (((size_t)(b * 8 + h) * 512) + i0 + w * 16 + lr) * 64 + lg * 8;
        qfh[0] = *(const bf16x8*)&qh[base];
        qfh[1] = *(const bf16x8*)&qh[base + 32];
    }

    float mrow[4], lrow[4];
    f32x4 oacc[4];
    #pragma unroll
    for (int r = 0; r < 4; ++r) { mrow[r] = -3.0e38f; lrow[r] = 0.f; }
    #pragma unroll
    for (int nb = 0; nb < 4; ++nb) oacc[nb] = (f32x4)0.f;

    for (int jt = 0; jt < ntiles; ++jt) {
        const int j0 = jt << 6;
        __syncthreads();
        #pragma unroll
        for (int i = 0; i < 2; ++i) {
            int flat = i * 256 + t;
            int m = flat >> 3, c = flat & 7;
            int lidx = m * 64 + ((c ^ (m & 7)) << 3);
            size_t kg = ((size_t)b * 512 + j0 + m) * 64 + c * 8;
            *(ushort8*)&sKh[lidx] = *(const ushort8*)&kh[kg];
            *(ushort8*)&sKl[lidx] = *(const ushort8*)&kl[kg];
            size_t vg = ((size_t)b * 64 + m) * 512 + j0 + c * 8;
            *(ushort8*)&sVT[lidx] = *(const ushort8*)&vT[vg];
        }
        __syncthreads();

        f32x4 accS[4];
        #pragma unroll
        for (int nb = 0; nb < 4; ++nb) accS[nb] = (f32x4)0.f;
        #pragma unroll
        for (int ks = 0; ks < 2; ++ks) {
            const int c = ks * 4 + lg;
            #pragma unroll
            for (int nb = 0; nb < 4; ++nb) {
                int n = nb * 16 + lr;
                int lidx = n * 64 + ((c ^ (n & 7)) << 3);
                bf16x8 kfh = *(bf16x8*)&sKh[lidx];
                bf16x8 kfl = *(bf16x8*)&sKl[lidx];
                accS[nb] = __builtin_amdgcn_mfma_f32_16x16x32_bf16(qfh[ks], kfh, accS[nb], 0, 0, 0);
                accS[nb] = __builtin_amdgcn_mfma_f32_16x16x32_bf16(qfh[ks], kfl, accS[nb], 0, 0, 0);
            }
        }

        #pragma unroll
        for (int nb = 0; nb < 4; ++nb) {
            if (j0 + nb * 16 + lr >= VL) {
                #pragma unroll
                for (int r = 0; r < 4; ++r) accS[nb][r] = -3.0e38f;
            }
        }

        #pragma unroll
        for (int r = 0; r < 4; ++r) {
            float rm = fmaxf(fmaxf(accS[0][r], accS[1][r]), fmaxf(accS[2][r], accS[3][r]));
            #pragma unroll
            for (int off = 8; off; off >>= 1) rm = fmaxf(rm, __shfl_xor(rm, off));
            float nm = fmaxf(mrow[r], rm);
            float scl = __expf(mrow[r] - nm);
            mrow[r] = nm;
            float ps = 0.f;
            #pragma unroll
            for (int nb = 0; nb < 4; ++nb) {
                float p = __expf(accS[nb][r] - nm);
                accS[nb][r] = p;
                ps += p;
            }
            lrow[r] = lrow[r] * scl + ps;
            #pragma unroll
            for (int nb = 0; nb < 4; ++nb) oacc[nb][r] *= scl;
        }

        #pragma unroll
        for (int nb = 0; nb < 4; ++nb) {
            int cc = nb * 2 + (lr >> 3);
            #pragma unroll
            for (int r = 0; r < 4; ++r) {
                int q = w * 16 + lg * 4 + r;
                int lidx = q * 64 + ((cc ^ (q & 7)) << 3) + (lr & 7);
                float hf2;
                sP[lidx] = bfhi(accS[nb][r], &hf2);
            }
        }

        #pragma unroll
        for (int ks = 0; ks < 2; ++ks) {
            const int c = ks * 4 + lg;
            int qrow = w * 16 + lr;
            int plidx = qrow * 64 + ((c ^ (qrow & 7)) << 3);
            bf16x8 pf = *(bf16x8*)&sP[plidx];
            #pragma unroll
            for (int nb = 0; nb < 4; ++nb) {
                int n = nb * 16 + lr;
                int lidx = n * 64 + ((c ^ (n & 7)) << 3);
                bf16x8 vf = *(bf16x8*)&sVT[lidx];
                oacc[nb] = __builtin_amdgcn_mfma_f32_16x16x32_bf16(pf, vf, oacc[nb], 0, 0, 0);
            }
        }
    }

    #pragma unroll
    for (int r = 0; r < 4; ++r) {
        float lt = lrow[r];
        #pragma unroll
        for (int off = 8; off; off >>= 1) lt += __shfl_xor(lt, off);
        float inv = 1.0f / lt;
        const int row = (b << 9) + i0 + w * 16 + lg * 4 + r;
        const size_t base = (size_t)row * DIMM + h * 64;
        #pragma unroll
        for (int nb = 0; nb < 4; ++nb) {
            float v = oacc[nb][r] * inv;
            float hf;
            ctxh[base + nb * 16 + lr] = bfhi(v, &hf);
        }
    }
}

// ------------------------------ pool ---------------------------------------
__global__ __launch_bounds__(512) void pool_part_k(const float* __restrict__ x,
                                                   float* __restrict__ psum,
                                                   float* __restrict__ pmax)
{
    const int seg = blockIdx.x;
    const int b   = blockIdx.y;
    const int d   = threadIdx.x;
    const float* xb = x + ((size_t)(b << 9) + (seg << 6)) * DIMM;
    float s = 0.f, m = -3.0e38f;
    for (int i = 0; i < 64; ++i) {
        float v = xb[(size_t)i * DIMM + d];
        s += v;
        m = fmaxf(m, v);
    }
    psum[((size_t)b * 8 + seg) * DIMM + d] = s;
    pmax[((size_t)b * 8 + seg) * DIMM + d] = m;
}

__global__ __launch_bounds__(512) void pool_comb_k(const float* __restrict__ psum,
                                                   const float* __restrict__ pmax,
                                                   float* __restrict__ out)
{
    const int b = blockIdx.x;
    const int d = threadIdx.x;
    float s = 0.f, m = -3.0e38f;
    #pragma unroll
    for (int seg = 0; seg < 8; ++seg) {
        s += psum[((size_t)b * 8 + seg) * DIMM + d];
        m = fmaxf(m, pmax[((size_t)b * 8 + seg) * DIMM + d]);
    }
    out[b * 1024 + d] = s * (1.0f / 512.0f);
    out[b * 1024 + 512 + d] = m;
}

// ---------------------------------------------------------------------------
extern "C" void kernel_launch(void* const* d_in, const int* in_sizes, int n_in,
                              void* d_out, int out_size, void* d_ws, size_t ws_size,
                              hipStream_t stream)
{
    const int*   page_in        = (const int*)d_in[0];
    const int*   item_in        = (const int*)d_in[1];
    const int*   item_meta_in   = (const int*)d_in[2];
    const int*   vl_in          = (const int*)d_in[3];
    const int*   page_meta_in   = (const int*)d_in[4];
    const float* pwide          = (const float*)d_in[5];
    const float* iwide          = (const float*)d_in[6];
    const float* page_emb       = (const float*)d_in[7];
    const float* page_meta_emb  = (const float*)d_in[8];
    const float* item_emb       = (const float*)d_in[9];
    const float* item_meta_emb  = (const float*)d_in[10];
    const float* item_pre_emb   = (const float*)d_in[11];
    const float* pW             = (const float*)d_in[12];
    const float* pb             = (const float*)d_in[13];
    const float* pg             = (const float*)d_in[14];
    const float* pbeta          = (const float*)d_in[15];
    const float* iW             = (const float*)d_in[16];
    const float* ib             = (const float*)d_in[17];
    const float* ig             = (const float*)d_in[18];
    const float* ibeta          = (const float*)d_in[19];
    const float* norm_g         = (const float*)d_in[20];
    const float* fused_W        = (const float*)d_in[21];
    const float* attn_out_W     = (const float*)d_in[22];
    const float* ff_out_W       = (const float*)d_in[23];
    float* out = (float*)d_out;

    float* ws  = (float*)d_ws;
    float* x    = ws;                                      // 16384*512 f32
    unsigned short* xnh = (unsigned short*)(x + (size_t)NROWS * DIMM);
    unsigned short* qhb = xnh + (size_t)NROWS * DIMM;      // q hi [b,h,s,64]
    unsigned short* hh   = qhb + (size_t)NROWS * DIMM;
    unsigned short* ctxh = hh + (size_t)NROWS * FFIN;
    float* psum = (float*)(ctxh + (size_t)NROWS * DIMM);
    float* pmax = psum + (size_t)NBATCH * 8 * DIMM;
    unsigned short* WqTh = (unsigned short*)(pmax + (size_t)NBATCH * 8 * DIMM);
    unsigned short* WqTl = WqTh + (size_t)QKVC * DIMM;     // 640x512
    unsigned short* WdTh = WqTl + (size_t)QKVC * DIMM;     // 4096x512 (hi only)
    unsigned short* WaTh = WdTh + (size_t)4096 * DIMM;     // 512x512 (hi only)
    unsigned short* WfTh = WaTh + (size_t)DIMM * DIMM;     // 512x2048 (hi only)
    unsigned short* khb  = WfTh + (size_t)DIMM * FFIN;     // 32x512x64
    unsigned short* klb  = khb + (size_t)NBATCH * SEQ * 64;
    unsigned short* vTb  = klb + (size_t)NBATCH * SEQ * 64; // 32x64x512
    float* cost = (float*)(vTb + (size_t)NBATCH * 64 * SEQ); // 512x32
    float* sint = cost + 512 * 32;

    build_x_k<<<NROWS, 512, 0, stream>>>(
        page_in, item_in, item_meta_in, page_meta_in, pwide, iwide,
        page_emb, page_meta_emb, item_emb, item_meta_emb, item_pre_emb,
        pW, pb, pg, pbeta, iW, ib, ig, ibeta, x);

    trig_k<<<64, 256, 0, stream>>>(cost, sint);

    for (int l = 0; l < 4; ++l) {
        const float* Wf  = fused_W    + (size_t)l * DIMM * NFUSED;
        const float* Wa  = attn_out_W + (size_t)l * DIMM * DIMM;
        const float* Wff = ff_out_W   + (size_t)l * FFIN * DIMM;
        const float* g   = norm_g     + (size_t)l * DIMM;

        ln_k<<<NROWS, 256, 0, stream>>>(x, xnh, g);

        wconv_all_k<<<912, 256, 0, stream>>>(
            Wf, Wa, Wff, WqTh, WqTl, WdTh, WaTh, WfTh);

        mfma_qkv_rope_k<<<dim3(QKVC / 64, NROWS / 128), 256, 0, stream>>>(
            xnh, WqTh, WqTl, cost, sint, qhb, khb, klb, vTb);

        mfma_dual_silu_k<<<dim3(FFIN / 64, NROWS / 128), 256, 0, stream>>>(
            xnh, WdTh, hh);

        attn_mfma_k<<<dim3(SEQ / 64, NHEAD, NBATCH), 256, 0, stream>>>(
            qhb, khb, klb, vTb, ctxh, vl_in);

        mfma_out_k<<<512, 256, 0, stream>>>(
            ctxh, WaTh, hh, WfTh, x);
    }

    pool_part_k<<<dim3(8, NBATCH), 512, 0, stream>>>(x, psum, pmax);
    pool_comb_k<<<NBATCH, 512, 0, stream>>>(psum, pmax, out);
}

// Round 31
// 912.307 us; speedup vs baseline: 1.0772x; 1.0772x over previous
//
#include <hip/hip_runtime.h>
#include <math.h>

// ---------------------------------------------------------------------------
// ParallelTransformerAEP forward.
// R30: dual_silu reverted to R28's 16x16 MFMA (R29's 32x32 introduced 8.4M
//      LDS bank conflicts, +7us); h store changed from nontemporal to plain
//      (NT forced 67MB h through HBM twice; L3 (256MB) can hold it between
//      dual_silu and out_k). Rest identical to R28 (949.8 us best).
// ---------------------------------------------------------------------------

namespace {
constexpr int SEQ    = 512;
constexpr int NBATCH = 32;
constexpr int DIMM   = 512;
constexpr int NHEAD  = 8;
constexpr int FFIN   = 2048;
constexpr int NFUSED = 4736;
constexpr int NROWS  = NBATCH * SEQ;   // 16384
constexpr int QKVC   = 640;            // 512 q + 64 k + 64 v
}

typedef __bf16 bf16x8 __attribute__((ext_vector_type(8)));
typedef float f32x4 __attribute__((ext_vector_type(4)));
typedef unsigned short ushort8 __attribute__((ext_vector_type(8)));

static __device__ __forceinline__ unsigned short bfhi(float v, float* hf) {
    __bf16 h = (__bf16)v;
    *hf = (float)h;
    return __builtin_bit_cast(unsigned short, h);
}
static __device__ __forceinline__ unsigned short bflo(float v, float hf) {
    __bf16 l = (__bf16)(v - hf);
    return __builtin_bit_cast(unsigned short, l);
}

// 16-byte global->LDS DMA; LDS dest = wave-uniform base + lane*16.
static __device__ __forceinline__ void gload16(const unsigned short* g,
                                               unsigned short* l) {
    __builtin_amdgcn_global_load_lds(
        (const __attribute__((address_space(1))) void*)g,
        (__attribute__((address_space(3))) void*)l,
        16, 0, 0);
}

// ------------------------- build x = page * item ---------------------------
__global__ __launch_bounds__(512) void build_x_k(
    const int* __restrict__ page_in, const int* __restrict__ item_in,
    const int* __restrict__ item_meta_in, const int* __restrict__ page_meta_in,
    const float* __restrict__ pwide, const float* __restrict__ iwide,
    const float* __restrict__ page_emb, const float* __restrict__ page_meta_emb,
    const float* __restrict__ item_emb, const float* __restrict__ item_meta_emb,
    const float* __restrict__ item_pre_emb,
    const float* __restrict__ pW, const float* __restrict__ pb,
    const float* __restrict__ pg, const float* __restrict__ pbeta,
    const float* __restrict__ iW, const float* __restrict__ ib,
    const float* __restrict__ ig, const float* __restrict__ ibeta,
    float* __restrict__ x)
{
    const int row = blockIdx.x;
    const int b = row >> 9;
    const int s = row & 511;
    const int d = threadIdx.x;
    const float BNS = 0.9999950000374997f;   // 1/sqrt(1+1e-5)

    float pv, iv;
    if (d < 384) {
        pv = page_emb[(size_t)page_in[row] * 384 + d];
    } else if (d < 448) {
        pv = page_meta_emb[(size_t)page_meta_in[row] * 64 + (d - 384)];
    } else {
        const int dd = d - 448;
        float acc = pb[dd];
        #pragma unroll
        for (int c = 0; c < 8; ++c) {
            float w  = pwide[((size_t)b * 8 + c) * SEQ + s];
            float wn = w * BNS * pg[c] + pbeta[c];
            acc += wn * pW[c * 64 + dd];
        }
        pv = acc > 0.f ? acc : 0.2f * acc;
    }
    if (d < 320) {
        iv = item_emb[(size_t)item_in[row] * 320 + d];
    } else if (d < 384) {
        iv = item_meta_emb[(size_t)item_meta_in[row] * 64 + (d - 320)];
    } else if (d < 448) {
        iv = item_pre_emb[(size_t)item_in[row] * 64 + (d - 384)];
    } else {
        const int dd = d - 448;
        float acc = ib[dd];
        #pragma unroll
        for (int c = 0; c < 8; ++c) {
            float w  = iwide[((size_t)b * 8 + c) * SEQ + s];
            float wn = w * BNS * ig[c] + ibeta[c];
            acc += wn * iW[c * 64 + dd];
        }
        iv = acc > 0.f ? acc : 0.2f * acc;
    }
    x[(size_t)row * DIMM + d] = pv * iv;
}

// ------------------------------ trig table ---------------------------------
__global__ __launch_bounds__(256) void trig_k(float* __restrict__ cost,
                                              float* __restrict__ sint)
{
    const int idx = blockIdx.x * 256 + threadIdx.x;   // 16384 = 512 x 32
    const int s = idx >> 5, j = idx & 31;
    float invf = powf(10000.0f, -(float)j * (1.0f / 32.0f));
    float ang = (float)s * invf;
    float sn, cs;
    sincosf(ang, &sn, &cs);
    cost[idx] = cs;
    sint[idx] = sn;
}

// ------------------------------ LayerNorm -> bf16 (hi only) ----------------
__global__ __launch_bounds__(256) void ln_k(const float* __restrict__ x,
                                            unsigned short* __restrict__ xnh,
                                            const float* __restrict__ g)
{
    const int row = blockIdx.x;
    const int t = threadIdx.x;
    const float* xr = x + (size_t)row * DIMM;
    __shared__ float red[4];

    float v0 = xr[t], v1 = xr[t + 256];
    float s = v0 + v1;
    #pragma unroll
    for (int o = 32; o; o >>= 1) s += __shfl_xor(s, o);
    if ((t & 63) == 0) red[t >> 6] = s;
    __syncthreads();
    float mu = (red[0] + red[1] + red[2] + red[3]) * (1.0f / 512.0f);
    __syncthreads();

    float d0 = v0 - mu, d1 = v1 - mu;
    float vs = d0 * d0 + d1 * d1;
    #pragma unroll
    for (int o = 32; o; o >>= 1) vs += __shfl_xor(vs, o);
    if ((t & 63) == 0) red[t >> 6] = vs;
    __syncthreads();
    float var = (red[0] + red[1] + red[2] + red[3]) * (1.0f / 512.0f);
    float r = 1.0f / sqrtf(var + 1e-5f);

    const size_t base = (size_t)row * DIMM;
    float o0 = d0 * r * g[t];
    float o1 = d1 * r * g[t + 256];
    float hf;
    xnh[base + t]       = bfhi(o0, &hf);
    xnh[base + t + 256] = bfhi(o1, &hf);
}

// ------- fused weight transpose+split for all four regions of one layer ----
__global__ __launch_bounds__(256) void wconv_all_k(
    const float* __restrict__ Wf, const float* __restrict__ Wa,
    const float* __restrict__ Wff,
    unsigned short* __restrict__ WqTh, unsigned short* __restrict__ WqTl,
    unsigned short* __restrict__ WdTh, unsigned short* __restrict__ WaTh,
    unsigned short* __restrict__ WfTh)
{
    __shared__ float tile[64][65];
    const int bid = blockIdx.x;
    const int t   = threadIdx.x;

    const float* W;
    unsigned short* Th;
    unsigned short* Tl = nullptr;
    int ldw, col0, ldt, nt, kt;
    bool split = false;

    if (bid < 80) {                 // Wq
        W = Wf; ldw = NFUSED; col0 = 0; Th = WqTh; Tl = WqTl; ldt = DIMM;
        split = true;
        nt = bid % 10; kt = bid / 10;
    } else if (bid < 592) {         // Wd
        int b = bid - 80;
        W = Wf; ldw = NFUSED; col0 = 640; Th = WdTh; ldt = DIMM;
        nt = b & 63; kt = b >> 6;
    } else if (bid < 656) {         // Wa
        int b = bid - 592;
        W = Wa; ldw = DIMM; col0 = 0; Th = WaTh; ldt = DIMM;
        nt = b & 7; kt = b >> 3;
    } else {                        // Wff
        int b = bid - 656;
        W = Wff; ldw = DIMM; col0 = 0; Th = WfTh; ldt = FFIN;
        nt = b & 7; kt = b >> 3;
    }
    nt <<= 6; kt <<= 6;

    #pragma unroll
    for (int i = 0; i < 16; ++i) {
        int flat = i * 256 + t;
        int r = flat >> 6, c = flat & 63;
        tile[r][c] = W[(size_t)(kt + r) * ldw + col0 + nt + c];
    }
    __syncthreads();
    #pragma unroll
    for (int i = 0; i < 2; ++i) {
        int flat = i * 256 + t;
        int n = flat >> 3, ck = (flat & 7) << 3;
        ushort8 hv, lv;
        #pragma unroll
        for (int j = 0; j < 8; ++j) {
            float v = tile[ck + j][n];
            float hf;
            hv[j] = bfhi(v, &hf);
            if (split) lv[j] = bflo(v, hf);
        }
        size_t o = (size_t)(nt + n) * ldt + kt + ck;
        *(ushort8*)&Th[o] = hv;
        if (split) *(ushort8*)&Tl[o] = lv;
    }
}

// ---- MFMA qkv GEMM + fused RoPE epilogue ----------------------------------
__global__ __launch_bounds__(256, 4) void mfma_qkv_rope_k(
    const unsigned short* __restrict__ Ah,
    const unsigned short* __restrict__ BTh, const unsigned short* __restrict__ BTl,
    const float* __restrict__ cost, const float* __restrict__ sint,
    unsigned short* __restrict__ qh,
    unsigned short* __restrict__ kh, unsigned short* __restrict__ kl,
    unsigned short* __restrict__ vT)
{
    __shared__ unsigned short smem[128 * 64 + 64 * 64 + 64 * 64];  // 32 KB
    unsigned short* sA  = smem;
    unsigned short* sBh = smem + 128 * 64;
    unsigned short* sBl = smem + 128 * 64 + 64 * 64;
    float* tileF = (float*)smem;   // 8192 fp32 = full 32 KB, reused post-loop

    const int n0 = blockIdx.x << 6;
    const int m0 = blockIdx.y << 7;
    const int t  = threadIdx.x;
    const int l  = t & 63;
    const int w  = t >> 6;
    const int wm = w >> 1, wn = w & 1;
    const int lr = l & 15, lg = l >> 4;
    const int lm = l >> 3;      // row within 8-row DMA segment
    const int lc = l & 7;       // 16B chunk within row

    f32x4 acc[4][2];
    #pragma unroll
    for (int fm = 0; fm < 4; ++fm)
        #pragma unroll
        for (int fn = 0; fn < 2; ++fn) acc[fm][fn] = (f32x4)0.f;

    for (int k0 = 0; k0 < DIMM; k0 += 64) {
        __syncthreads();
        // A: 16 segments of 8 rows; wave w handles segments w*4..w*4+3
        #pragma unroll
        for (int j = 0; j < 4; ++j) {
            int seg = w * 4 + j;
            int m = seg * 8 + lm;
            gload16(&Ah[(size_t)(m0 + m) * DIMM + k0 + ((lc ^ (m & 7)) << 3)],
                    &sA[seg * 512]);
        }
        // Bh/Bl: 8 segments each; wave w handles segments w*2..w*2+1
        #pragma unroll
        for (int j = 0; j < 2; ++j) {
            int seg = w * 2 + j;
            int n = seg * 8 + lm;
            int soff = (lc ^ (n & 7)) << 3;
            gload16(&BTh[(size_t)(n0 + n) * DIMM + k0 + soff], &sBh[seg * 512]);
            gload16(&BTl[(size_t)(n0 + n) * DIMM + k0 + soff], &sBl[seg * 512]);
        }
        __syncthreads();

        #pragma unroll
        for (int kk = 0; kk < 2; ++kk) {
            const int c = kk * 4 + lg;
            bf16x8 af[4];
            #pragma unroll
            for (int fm = 0; fm < 4; ++fm) {
                int m = wm * 64 + fm * 16 + lr;
                int lidx = m * 64 + ((c ^ (m & 7)) << 3);
                af[fm] = *(bf16x8*)&sA[lidx];
            }
            bf16x8 bh[2], bl[2];
            #pragma unroll
            for (int fn = 0; fn < 2; ++fn) {
                int n = wn * 32 + fn * 16 + lr;
                int lidx = n * 64 + ((c ^ (n & 7)) << 3);
                bh[fn] = *(bf16x8*)&sBh[lidx];
                bl[fn] = *(bf16x8*)&sBl[lidx];
            }
            #pragma unroll
            for (int fm = 0; fm < 4; ++fm)
                #pragma unroll
                for (int fn = 0; fn < 2; ++fn) {
                    acc[fm][fn] = __builtin_amdgcn_mfma_f32_16x16x32_bf16(af[fm], bh[fn], acc[fm][fn], 0, 0, 0);
                    acc[fm][fn] = __builtin_amdgcn_mfma_f32_16x16x32_bf16(af[fm], bl[fn], acc[fm][fn], 0, 0, 0);
                }
        }
    }

    // ---- epilogue: acc -> fp32 LDS tile, rotation swizzle col=(d+s)&63 ----
    __syncthreads();
    #pragma unroll
    for (int fm = 0; fm < 4; ++fm)
        #pragma unroll
        for (int fn = 0; fn < 2; ++fn) {
            const int nl = wn * 32 + fn * 16 + lr;
            #pragma unroll
            for (int r = 0; r < 4; ++r) {
                const int ml = wm * 64 + fm * 16 + lg * 4 + r;
                tileF[ml * 64 + ((nl + ml) & 63)] = acc[fm][fn][r];
            }
        }
    __syncthreads();

    const int tid = n0 >> 6;        // 0..7 q heads, 8 = k, 9 = v
    const int gb  = m0 >> 9;        // batch (128-row tile stays in one batch)
    const int sb  = m0 & 511;       // s base within batch

    if (tid < 8) {
        // q: rope + 1/8 scale -> qh[((gb*8+tid)*512+s)*64+d]
        #pragma unroll 4
        for (int i = 0; i < 32; ++i) {
            int flat = i * 256 + t;
            int d = flat & 63, sl = flat >> 6;
            int s = sb + sl;
            float v  = tileF[sl * 64 + ((d + sl) & 63)];
            float vp = tileF[sl * 64 + (((d ^ 32) + sl) & 63)];
            float cs = cost[s * 32 + (d & 31)];
            float sn = sint[s * 32 + (d & 31)];
            float sgn = (d < 32) ? -1.f : 1.f;
            float o = (v * cs + sgn * vp * sn) * 0.125f;
            float hf;
            qh[(((size_t)gb * 8 + tid) * 512 + s) * 64 + d] = bfhi(o, &hf);
        }
    } else if (tid == 8) {
        // k: rope (no scale) -> kh/kl split
        #pragma unroll 4
        for (int i = 0; i < 32; ++i) {
            int flat = i * 256 + t;
            int d = flat & 63, sl = flat >> 6;
            int s = sb + sl;
            float v  = tileF[sl * 64 + ((d + sl) & 63)];
            float vp = tileF[sl * 64 + (((d ^ 32) + sl) & 63)];
            float cs = cost[s * 32 + (d & 31)];
            float sn = sint[s * 32 + (d & 31)];
            float sgn = (d < 32) ? -1.f : 1.f;
            float o = v * cs + sgn * vp * sn;
            float hf;
            size_t idx = ((size_t)gb * 512 + s) * 64 + d;
            kh[idx] = bfhi(o, &hf);
            kl[idx] = bflo(o, hf);
        }
    } else {
        // v: transposed store vT[(gb*64+d)*512 + s] (lanes sweep s: coalesced)
        #pragma unroll 4
        for (int i = 0; i < 32; ++i) {
            int flat = i * 256 + t;
            int sl = flat & 127, d = flat >> 7;
            float v = tileF[sl * 64 + ((d + sl) & 63)];
            float hf;
            vT[((size_t)gb * 64 + d) * 512 + sb + sl] = bfhi(v, &hf);
        }
    }
}

// ----- MFMA out GEMM: x += ctx@Wa + h@Wff (single bf16, 2-pass K) ----------
// BM=64 x BN=256; 1D grid 512 with XCD-chunked swizzle.
// Counted-vmcnt double buffer (R28). LDS 80KB, lb(256,2).
__global__ __launch_bounds__(256, 2) void mfma_out_k(
    const unsigned short* __restrict__ A1,
    const unsigned short* __restrict__ B1,
    const unsigned short* __restrict__ A2,
    const unsigned short* __restrict__ B2,
    float* __restrict__ X)
{
    __shared__ unsigned short sA[2][64 * 64];
    __shared__ unsigned short sB[2][256 * 64];

    const int bid = blockIdx.x;
    const int swz = (bid & 7) * 64 + (bid >> 3);
    const int n0 = (swz & 1) << 8;
    const int m0 = (swz >> 1) << 6;

    const int t  = threadIdx.x;
    const int l  = t & 63;
    const int w  = t >> 6;
    const int lr = l & 15, lg = l >> 4;
    const int lm = l >> 3;      // row within 8-row DMA segment
    const int lc = l & 7;       // 16B chunk within row

    f32x4 acc[4][4];
    #pragma unroll
    for (int fm = 0; fm < 4; ++fm)
        #pragma unroll
        for (int fn = 0; fn < 4; ++fn) acc[fm][fn] = (f32x4)0.f;

    // flattened K-tiles: 0..7 = pass0 (ctx@Wa, K=512), 8..39 = pass1 (h@Wff)
    auto stage = [&](int buf, int tt) {
        const unsigned short* pA = (tt < 8) ? A1 : A2;
        const unsigned short* pB = (tt < 8) ? B1 : B2;
        const int lda = (tt < 8) ? DIMM : FFIN;
        const int KK  = (tt < 8) ? DIMM : FFIN;
        const int k0  = ((tt < 8) ? tt : tt - 8) << 6;
        #pragma unroll
        for (int j = 0; j < 2; ++j) {
            int seg = w * 2 + j;
            int m = seg * 8 + lm;
            gload16(&pA[(size_t)(m0 + m) * lda + k0 + ((lc ^ (m & 7)) << 3)],
                    &sA[buf][seg * 512]);
        }
        #pragma unroll
        for (int j = 0; j < 8; ++j) {
            int seg = w * 8 + j;
            int n = seg * 8 + lm;
            gload16(&pB[(size_t)(n0 + n) * KK + k0 + ((lc ^ (n & 7)) << 3)],
                    &sB[buf][seg * 512]);
        }
    };

    auto compute = [&](int buf) {
        #pragma unroll
        for (int kk = 0; kk < 2; ++kk) {
            const int c = kk * 4 + lg;
            bf16x8 af[4];
            #pragma unroll
            for (int fm = 0; fm < 4; ++fm) {
                int m = fm * 16 + lr;
                int lidx = m * 64 + ((c ^ (m & 7)) << 3);
                af[fm] = *(bf16x8*)&sA[buf][lidx];
            }
            bf16x8 bfr[4];
            #pragma unroll
            for (int fn = 0; fn < 4; ++fn) {
                int n = w * 64 + fn * 16 + lr;
                int lidx = n * 64 + ((c ^ (n & 7)) << 3);
                bfr[fn] = *(bf16x8*)&sB[buf][lidx];
            }
            #pragma unroll
            for (int fm = 0; fm < 4; ++fm)
                #pragma unroll
                for (int fn = 0; fn < 4; ++fn)
                    acc[fm][fn] = __builtin_amdgcn_mfma_f32_16x16x32_bf16(af[fm], bfr[fn], acc[fm][fn], 0, 0, 0);
        }
    };

    stage(0, 0);
    asm volatile("s_waitcnt vmcnt(0)" ::: "memory");
    __builtin_amdgcn_sched_barrier(0);
    __builtin_amdgcn_s_barrier();
    int cur = 0;
    for (int tt = 0; tt < 39; ++tt) {
        stage(cur ^ 1, tt + 1);    // 10 DMAs issued, left in flight
        asm volatile("s_waitcnt vmcnt(10)" ::: "memory");  // tile tt landed
        __builtin_amdgcn_sched_barrier(0);
        __builtin_amdgcn_s_barrier();
        compute(cur);
        __builtin_amdgcn_s_barrier();   // all reads of buf done before overwrite
        cur ^= 1;
    }
    asm volatile("s_waitcnt vmcnt(0)" ::: "memory");
    __builtin_amdgcn_sched_barrier(0);
    __builtin_amdgcn_s_barrier();
    compute(cur);                  // last tile

    #pragma unroll
    for (int fm = 0; fm < 4; ++fm)
        #pragma unroll
        for (int fn = 0; fn < 4; ++fn) {
            const int n = n0 + w * 64 + fn * 16 + lr;
            #pragma unroll
            for (int r = 0; r < 4; ++r) {
                const int m = m0 + fm * 16 + lg * 4 + r;
                X[(size_t)m * DIMM + n] += acc[fm][fn][r];
            }
        }
}

// --- MFMA dual GEMM: h = silu(A@Wg)*(A@Wx), single bf16 -> bf16 ------------
// BM=128 x BN=64, lb(256,4), 16x16x32 MFMA. gload16 staging (rule #21).
// R30: plain stores for h (NT forced HBM roundtrip; L3 holds h for out_k).
__global__ __launch_bounds__(256, 4) void mfma_dual_silu_k(
    const unsigned short* __restrict__ Ah,
    const unsigned short* __restrict__ WTh,
    unsigned short* __restrict__ Hh)
{
    __shared__ unsigned short sA[128 * 64];
    __shared__ unsigned short sBx[64 * 64];
    __shared__ unsigned short sBg[64 * 64];

    const int n0 = blockIdx.x << 6;
    const int m0 = blockIdx.y << 7;
    const int t  = threadIdx.x;
    const int l  = t & 63;
    const int w  = t >> 6;
    const int wm = w >> 1, wn = w & 1;
    const int lr = l & 15, lg = l >> 4;
    const int lm = l >> 3;      // row within 8-row DMA segment
    const int lc = l & 7;       // 16B chunk within row

    f32x4 accX[4][2], accG[4][2];
    #pragma unroll
    for (int fm = 0; fm < 4; ++fm)
        #pragma unroll
        for (int fn = 0; fn < 2; ++fn) {
            accX[fm][fn] = (f32x4)0.f;
            accG[fm][fn] = (f32x4)0.f;
        }

    for (int k0 = 0; k0 < DIMM; k0 += 64) {
        __syncthreads();
        // A: 16 segments of 8 rows; wave w handles segments w*4..w*4+3
        #pragma unroll
        for (int j = 0; j < 4; ++j) {
            int seg = w * 4 + j;
            int m = seg * 8 + lm;
            gload16(&Ah[(size_t)(m0 + m) * DIMM + k0 + ((lc ^ (m & 7)) << 3)],
                    &sA[seg * 512]);
        }
        // Bx/Bg: 8 segments each; wave w handles segments w*2..w*2+1
        #pragma unroll
        for (int j = 0; j < 2; ++j) {
            int seg = w * 2 + j;
            int n = seg * 8 + lm;
            int soff = (lc ^ (n & 7)) << 3;
            gload16(&WTh[(size_t)(n0 + n) * DIMM + k0 + soff], &sBx[seg * 512]);
            gload16(&WTh[(size_t)(2048 + n0 + n) * DIMM + k0 + soff], &sBg[seg * 512]);
        }
        __syncthreads();

        #pragma unroll
        for (int kk = 0; kk < 2; ++kk) {
            const int c = kk * 4 + lg;
            bf16x8 af[4];
            #pragma unroll
            for (int fm = 0; fm < 4; ++fm) {
                int m = wm * 64 + fm * 16 + lr;
                int lidx = m * 64 + ((c ^ (m & 7)) << 3);
                af[fm] = *(bf16x8*)&sA[lidx];
            }
            bf16x8 bx[2], bg[2];
            #pragma unroll
            for (int fn = 0; fn < 2; ++fn) {
                int n = wn * 32 + fn * 16 + lr;
                int lidx = n * 64 + ((c ^ (n & 7)) << 3);
                bx[fn] = *(bf16x8*)&sBx[lidx];
                bg[fn] = *(bf16x8*)&sBg[lidx];
            }
            #pragma unroll
            for (int fm = 0; fm < 4; ++fm)
                #pragma unroll
                for (int fn = 0; fn < 2; ++fn) {
                    accX[fm][fn] = __builtin_amdgcn_mfma_f32_16x16x32_bf16(af[fm], bx[fn], accX[fm][fn], 0, 0, 0);
                    accG[fm][fn] = __builtin_amdgcn_mfma_f32_16x16x32_bf16(af[fm], bg[fn], accG[fm][fn], 0, 0, 0);
                }
        }
    }

    // epilogue: silu into LDS tile with staging-style swizzle
    __syncthreads();
    #pragma unroll
    for (int fm = 0; fm < 4; ++fm)
        #pragma unroll
        for (int fn = 0; fn < 2; ++fn) {
            const int nl = wn * 32 + fn * 16 + lr;
            const int cc = nl >> 3;
            #pragma unroll
            for (int r = 0; r < 4; ++r) {
                const int ml = wm * 64 + fm * 16 + lg * 4 + r;
                float gv = accG[fm][fn][r];
                float xv = accX[fm][fn][r];
                float sig = 1.0f / (1.0f + __expf(-gv));
                float hv = gv * sig * xv;
                float hf;
                sA[ml * 64 + ((cc ^ (ml & 7)) << 3) + (nl & 7)] = bfhi(hv, &hf);
            }
        }
    __syncthreads();
    // coalesced 16B stores (plain: keep h in L2/L3 for mfma_out_k)
    #pragma unroll
    for (int i = 0; i < 4; ++i) {
        int flat = i * 256 + t;
        int m = flat >> 3, c = flat & 7;
        ushort8 v = *(ushort8*)&sA[m * 64 + ((c ^ (m & 7)) << 3)];
        *(ushort8*)&Hh[(size_t)(m0 + m) * FFIN + n0 + c * 8] = v;
    }
}

// ------------------- attention: MFMA flash (per b,h,64 q-rows) -------------
// Masked-tile skip; QK = qh*(kh+kl) 2-product.
__global__ __launch_bounds__(256) void attn_mfma_k(
    const unsigned short* __restrict__ qh,
    const unsigned short* __restrict__ kh, const unsigned short* __restrict__ kl,
    const unsigned short* __restrict__ vT,
    unsigned short* __restrict__ ctxh,
    const int* __restrict__ vl)
{
    __shared__ unsigned short sKh[64 * 64];
    __shared__ unsigned short sKl[64 * 64];
    __shared__ unsigned short sVT[64 * 64];
    __shared__ unsigned short sP[64 * 64];

    const int i0 = blockIdx.x << 6;
    const int h  = blockIdx.y;
    const int b  = blockIdx.z;
    const int t  = threadIdx.x;
    const int l  = t & 63;
    const int w  = t >> 6;
    const int lr = l & 15, lg = l >> 4;
    const int VL = vl[b];
    const int ntiles = (VL + 63) >> 6;   // fully-masked tiles contribute 0

    bf16x8 qfh[2];
    {
        size_t base = (((size_t)(b * 8 + h) * 512) + i0 + w * 16 + lr) * 64 + lg * 8;
        qfh[0] = *(const bf16x8*)&qh[base];
        qfh[1] = *(const bf16x8*)&qh[base + 32];
    }

    float mrow[4], lrow[4];
    f32x4 oacc[4];
    #pragma unroll
    for (int r = 0; r < 4; ++r) { mrow[r] = -3.0e38f; lrow[r] = 0.f; }
    #pragma unroll
    for (int nb = 0; nb < 4; ++nb) oacc[nb] = (f32x4)0.f;

    for (int jt = 0; jt < ntiles; ++jt) {
        const int j0 = jt << 6;
        __syncthreads();
        #pragma unroll
        for (int i = 0; i < 2; ++i) {
            int flat = i * 256 + t;
            int m = flat >> 3, c = flat & 7;
            int lidx = m * 64 + ((c ^ (m & 7)) << 3);
            size_t kg = ((size_t)b * 512 + j0 + m) * 64 + c * 8;
            *(ushort8*)&sKh[lidx] = *(const ushort8*)&kh[kg];
            *(ushort8*)&sKl[lidx] = *(const ushort8*)&kl[kg];
            size_t vg = ((size_t)b * 64 + m) * 512 + j0 + c * 8;
            *(ushort8*)&sVT[lidx] = *(const ushort8*)&vT[vg];
        }
        __syncthreads();

        f32x4 accS[4];
        #pragma unroll
        for (int nb = 0; nb < 4; ++nb) accS[nb] = (f32x4)0.f;
        #pragma unroll
        for (int ks = 0; ks < 2; ++ks) {
            const int c = ks * 4 + lg;
            #pragma unroll
            for (int nb = 0; nb < 4; ++nb) {
                int n = nb * 16 + lr;
                int lidx = n * 64 + ((c ^ (n & 7)) << 3);
                bf16x8 kfh = *(bf16x8*)&sKh[lidx];
                bf16x8 kfl = *(bf16x8*)&sKl[lidx];
                accS[nb] = __builtin_amdgcn_mfma_f32_16x16x32_bf16(qfh[ks], kfh, accS[nb], 0, 0, 0);
                accS[nb] = __builtin_amdgcn_mfma_f32_16x16x32_bf16(qfh[ks], kfl, accS[nb], 0, 0, 0);
            }
        }

        #pragma unroll
        for (int nb = 0; nb < 4; ++nb) {
            if (j0 + nb * 16 + lr >= VL) {
                #pragma unroll
                for (int r = 0; r < 4; ++r) accS[nb][r] = -3.0e38f;
            }
        }

        #pragma unroll
        for (int r = 0; r < 4; ++r) {
            float rm = fmaxf(fmaxf(accS[0][r], accS[1][r]), fmaxf(accS[2][r], accS[3][r]));
            #pragma unroll
            for (int off = 8; off; off >>= 1) rm = fmaxf(rm, __shfl_xor(rm, off));
            float nm = fmaxf(mrow[r], rm);
            float scl = __expf(mrow[r] - nm);
            mrow[r] = nm;
            float ps = 0.f;
            #pragma unroll
            for (int nb = 0; nb < 4; ++nb) {
                float p = __expf(accS[nb][r] - nm);
                accS[nb][r] = p;
                ps += p;
            }
            lrow[r] = lrow[r] * scl + ps;
            #pragma unroll
            for (int nb = 0; nb < 4; ++nb) oacc[nb][r] *= scl;
        }

        #pragma unroll
        for (int nb = 0; nb < 4; ++nb) {
            int cc = nb * 2 + (lr >> 3);
            #pragma unroll
            for (int r = 0; r < 4; ++r) {
                int q = w * 16 + lg * 4 + r;
                int lidx = q * 64 + ((cc ^ (q & 7)) << 3) + (lr & 7);
                float hf2;
                sP[lidx] = bfhi(accS[nb][r], &hf2);
            }
        }

        #pragma unroll
        for (int ks = 0; ks < 2; ++ks) {
            const int c = ks * 4 + lg;
            int qrow = w * 16 + lr;
            int plidx = qrow * 64 + ((c ^ (qrow & 7)) << 3);
            bf16x8 pf = *(bf16x8*)&sP[plidx];
            #pragma unroll
            for (int nb = 0; nb < 4; ++nb) {
                int n = nb * 16 + lr;
                int lidx = n * 64 + ((c ^ (n & 7)) << 3);
                bf16x8 vf = *(bf16x8*)&sVT[lidx];
                oacc[nb] = __builtin_amdgcn_mfma_f32_16x16x32_bf16(pf, vf, oacc[nb], 0, 0, 0);
            }
        }
    }

    #pragma unroll
    for (int r = 0; r < 4; ++r) {
        float lt = lrow[r];
        #pragma unroll
        for (int off = 8; off; off >>= 1) lt += __shfl_xor(lt, off);
        float inv = 1.0f / lt;
        const int row = (b << 9) + i0 + w * 16 + lg * 4 + r;
        const size_t base = (size_t)row * DIMM + h * 64;
        #pragma unroll
        for (int nb = 0; nb < 4; ++nb) {
            float v = oacc[nb][r] * inv;
            float hf;
            ctxh[base + nb * 16 + lr] = bfhi(v, &hf);
        }
    }
}

// ------------------------------ pool ---------------------------------------
__global__ __launch_bounds__(512) void pool_part_k(const float* __restrict__ x,
                                                   float* __restrict__ psum,
                                                   float* __restrict__ pmax)
{
    const int seg = blockIdx.x;
    const int b   = blockIdx.y;
    const int d   = threadIdx.x;
    const float* xb = x + ((size_t)(b << 9) + (seg << 6)) * DIMM;
    float s = 0.f, m = -3.0e38f;
    for (int i = 0; i < 64; ++i) {
        float v = xb[(size_t)i * DIMM + d];
        s += v;
        m = fmaxf(m, v);
    }
    psum[((size_t)b * 8 + seg) * DIMM + d] = s;
    pmax[((size_t)b * 8 + seg) * DIMM + d] = m;
}

__global__ __launch_bounds__(512) void pool_comb_k(const float* __restrict__ psum,
                                                   const float* __restrict__ pmax,
                                                   float* __restrict__ out)
{
    const int b = blockIdx.x;
    const int d = threadIdx.x;
    float s = 0.f, m = -3.0e38f;
    #pragma unroll
    for (int seg = 0; seg < 8; ++seg) {
        s += psum[((size_t)b * 8 + seg) * DIMM + d];
        m = fmaxf(m, pmax[((size_t)b * 8 + seg) * DIMM + d]);
    }
    out[b * 1024 + d] = s * (1.0f / 512.0f);
    out[b * 1024 + 512 + d] = m;
}

// ---------------------------------------------------------------------------
extern "C" void kernel_launch(void* const* d_in, const int* in_sizes, int n_in,
                              void* d_out, int out_size, void* d_ws, size_t ws_size,
                              hipStream_t stream)
{
    const int*   page_in        = (const int*)d_in[0];
    const int*   item_in        = (const int*)d_in[1];
    const int*   item_meta_in   = (const int*)d_in[2];
    const int*   vl_in          = (const int*)d_in[3];
    const int*   page_meta_in   = (const int*)d_in[4];
    const float* pwide          = (const float*)d_in[5];
    const float* iwide          = (const float*)d_in[6];
    const float* page_emb       = (const float*)d_in[7];
    const float* page_meta_emb  = (const float*)d_in[8];
    const float* item_emb       = (const float*)d_in[9];
    const float* item_meta_emb  = (const float*)d_in[10];
    const float* item_pre_emb   = (const float*)d_in[11];
    const float* pW             = (const float*)d_in[12];
    const float* pb             = (const float*)d_in[13];
    const float* pg             = (const float*)d_in[14];
    const float* pbeta          = (const float*)d_in[15];
    const float* iW             = (const float*)d_in[16];
    const float* ib             = (const float*)d_in[17];
    const float* ig             = (const float*)d_in[18];
    const float* ibeta          = (const float*)d_in[19];
    const float* norm_g         = (const float*)d_in[20];
    const float* fused_W        = (const float*)d_in[21];
    const float* attn_out_W     = (const float*)d_in[22];
    const float* ff_out_W       = (const float*)d_in[23];
    float* out = (float*)d_out;

    float* ws  = (float*)d_ws;
    float* x    = ws;                                      // 16384*512 f32
    unsigned short* xnh = (unsigned short*)(x + (size_t)NROWS * DIMM);
    unsigned short* qhb = xnh + (size_t)NROWS * DIMM;      // q hi [b,h,s,64]
    unsigned short* hh   = qhb + (size_t)NROWS * DIMM;
    unsigned short* ctxh = hh + (size_t)NROWS * FFIN;
    float* psum = (float*)(ctxh + (size_t)NROWS * DIMM);
    float* pmax = psum + (size_t)NBATCH * 8 * DIMM;
    unsigned short* WqTh = (unsigned short*)(pmax + (size_t)NBATCH * 8 * DIMM);
    unsigned short* WqTl = WqTh + (size_t)QKVC * DIMM;     // 640x512
    unsigned short* WdTh = WqTl + (size_t)QKVC * DIMM;     // 4096x512 (hi only)
    unsigned short* WaTh = WdTh + (size_t)4096 * DIMM;     // 512x512 (hi only)
    unsigned short* WfTh = WaTh + (size_t)DIMM * DIMM;     // 512x2048 (hi only)
    unsigned short* khb  = WfTh + (size_t)DIMM * FFIN;     // 32x512x64
    unsigned short* klb  = khb + (size_t)NBATCH * SEQ * 64;
    unsigned short* vTb  = klb + (size_t)NBATCH * SEQ * 64; // 32x64x512
    float* cost = (float*)(vTb + (size_t)NBATCH * 64 * SEQ); // 512x32
    float* sint = cost + 512 * 32;

    build_x_k<<<NROWS, 512, 0, stream>>>(
        page_in, item_in, item_meta_in, page_meta_in, pwide, iwide,
        page_emb, page_meta_emb, item_emb, item_meta_emb, item_pre_emb,
        pW, pb, pg, pbeta, iW, ib, ig, ibeta, x);

    trig_k<<<64, 256, 0, stream>>>(cost, sint);

    for (int l = 0; l < 4; ++l) {
        const float* Wf  = fused_W    + (size_t)l * DIMM * NFUSED;
        const float* Wa  = attn_out_W + (size_t)l * DIMM * DIMM;
        const float* Wff = ff_out_W   + (size_t)l * FFIN * DIMM;
        const float* g   = norm_g     + (size_t)l * DIMM;

        ln_k<<<NROWS, 256, 0, stream>>>(x, xnh, g);

        wconv_all_k<<<912, 256, 0, stream>>>(
            Wf, Wa, Wff, WqTh, WqTl, WdTh, WaTh, WfTh);

        mfma_qkv_rope_k<<<dim3(QKVC / 64, NROWS / 128), 256, 0, stream>>>(
            xnh, WqTh, WqTl, cost, sint, qhb, khb, klb, vTb);

        mfma_dual_silu_k<<<dim3(FFIN / 64, NROWS / 128), 256, 0, stream>>>(
            xnh, WdTh, hh);

        attn_mfma_k<<<dim3(SEQ / 64, NHEAD, NBATCH), 256, 0, stream>>>(
            qhb, khb, klb, vTb, ctxh, vl_in);

        mfma_out_k<<<512, 256, 0, stream>>>(
            ctxh, WaTh, hh, WfTh, x);
    }

    pool_part_k<<<dim3(8, NBATCH), 512, 0, stream>>>(x, psum, pmax);
    pool_comb_k<<<NBATCH, 512, 0, stream>>>(psum, pmax, out);
}